// Round 2
// baseline (162.148 us; speedup 1.0000x reference)
//
#include <hip/hip_runtime.h>

// GaussianRenderer: N=512 gaussians -> 256x256x3 f32 image.
// Kernel 1 (1 block): per-gaussian transform + conic + stable depth-rank,
//   writes sorted 12-float records to d_ws.
// Kernel 2: per-pixel front-to-back compositing, parallelized 8-way over the
//   gaussian chain (over-operator is associative), butterfly-combined via
//   __shfl_xor. 8 waves/SIMD occupancy.

constexpr int   NGMAX = 1024;   // LDS depth array bound (N=512 here)
constexpr int   REC   = 12;     // floats per sorted gaussian record (48B)
constexpr int   WIMG  = 256;
constexpr int   HIMG  = 256;
constexpr int   SPLIT = 8;      // chunks per pixel chain
constexpr float LOG2E = 1.4426950408889634f;
constexpr float INV2PI = 0.15915494309189535f;

__global__ __launch_bounds__(NGMAX) void gs_preprocess(
    const float* __restrict__ means3D, const float* __restrict__ covs3d,
    const float* __restrict__ colors,  const float* __restrict__ opac,
    const float* __restrict__ Km,      const float* __restrict__ Rm,
    const float* __restrict__ tvec,    float* __restrict__ recs, int N)
{
    __shared__ float s_depth[NGMAX];
    const int i = threadIdx.x;

    float Kl[9], Rl[9], tl[3];
    #pragma unroll
    for (int k = 0; k < 9; ++k) { Kl[k] = Km[k]; Rl[k] = Rm[k]; }
    tl[0] = tvec[0]; tl[1] = tvec[1]; tl[2] = tvec[2];

    float depth = 3.0e38f;
    float rec[REC];
    if (i < N) {
        const float m0 = means3D[i*3+0], m1 = means3D[i*3+1], m2 = means3D[i*3+2];
        float cam0 = Rl[0]*m0 + Rl[1]*m1 + Rl[2]*m2 + tl[0];
        float cam1 = Rl[3]*m0 + Rl[4]*m1 + Rl[5]*m2 + tl[1];
        float cam2 = Rl[6]*m0 + Rl[7]*m1 + Rl[8]*m2 + tl[2];
        const float Z = cam2;
        depth = fmaxf(Z, 1.0f);

        const float s0 = Kl[0]*cam0 + Kl[1]*cam1 + Kl[2]*cam2;
        const float s1 = Kl[3]*cam0 + Kl[4]*cam1 + Kl[5]*cam2;
        const float s2 = Kl[6]*cam0 + Kl[7]*cam1 + Kl[8]*cam2;
        const float mx = s0 / s2, my = s1 / s2;

        const float fx = Kl[0], fy = Kl[4];
        const float iz = 1.0f / Z;
        float J[2][3];
        J[0][0] = fx*iz; J[0][1] = 0.0f;  J[0][2] = -fx*cam0*iz*iz;
        J[1][0] = 0.0f;  J[1][1] = fy*iz; J[1][2] = -fy*cam1*iz*iz;

        float S[9];
        #pragma unroll
        for (int k = 0; k < 9; ++k) S[k] = covs3d[i*9+k];

        float RS[9], Cc[9];
        #pragma unroll
        for (int r = 0; r < 3; ++r)
            #pragma unroll
            for (int c = 0; c < 3; ++c)
                RS[r*3+c] = Rl[r*3+0]*S[0+c] + Rl[r*3+1]*S[3+c] + Rl[r*3+2]*S[6+c];
        #pragma unroll
        for (int r = 0; r < 3; ++r)
            #pragma unroll
            for (int c = 0; c < 3; ++c)
                Cc[r*3+c] = RS[r*3+0]*Rl[c*3+0] + RS[r*3+1]*Rl[c*3+1] + RS[r*3+2]*Rl[c*3+2];

        float JC[2][3];
        #pragma unroll
        for (int r = 0; r < 2; ++r)
            #pragma unroll
            for (int c = 0; c < 3; ++c)
                JC[r][c] = J[r][0]*Cc[0+c] + J[r][1]*Cc[3+c] + J[r][2]*Cc[6+c];

        const float c200 = JC[0][0]*J[0][0] + JC[0][1]*J[0][1] + JC[0][2]*J[0][2] + 1e-4f;
        const float c201 = JC[0][0]*J[1][0] + JC[0][1]*J[1][1] + JC[0][2]*J[1][2];
        const float c210 = JC[1][0]*J[0][0] + JC[1][1]*J[0][1] + JC[1][2]*J[0][2];
        const float c211 = JC[1][0]*J[1][0] + JC[1][1]*J[1][1] + JC[1][2]*J[1][2] + 1e-4f;

        const float det  = c200*c211 - c201*c210;
        const float idet = 1.0f / det;
        const float ia  = c211*idet;
        const float ibs = -(c201 + c210)*idet;   // inv01+inv10
        const float ic  = c200*idet;

        const bool valid = (depth > 1.0f) && (depth < 50.0f);
        const float nrm  = valid ? (INV2PI / sqrtf(det)) : 0.0f;

        rec[0] = mx;
        rec[1] = my;
        rec[2] = -0.5f*LOG2E*ia;    // A
        rec[3] = -0.5f*LOG2E*ibs;   // B (covers both off-diagonals)
        rec[4] = -0.5f*LOG2E*ic;    // C
        rec[5] = opac[i] * nrm;     // opacity*norm*valid folded
        rec[6] = colors[i*3+0];
        rec[7] = colors[i*3+1];
        rec[8] = colors[i*3+2];
        rec[9] = 0.0f; rec[10] = 0.0f; rec[11] = 0.0f;
    }

    s_depth[i] = depth;
    __syncthreads();

    if (i < N) {
        int rank = 0;
        for (int j = 0; j < N; ++j) {
            const float dj = s_depth[j];
            rank += (dj < depth) || (dj == depth && j < i);
        }
        float4* dst = (float4*)(recs + rank*REC);
        dst[0] = make_float4(rec[0], rec[1], rec[2],  rec[3]);
        dst[1] = make_float4(rec[4], rec[5], rec[6],  rec[7]);
        dst[2] = make_float4(rec[8], rec[9], rec[10], rec[11]);
    }
}

// 256 threads/block = 32 pixels x 8 chunks. Lane layout: chunk = lane&7,
// pixel = tid>>3. Each thread composites a contiguous 1/8 of the sorted
// gaussian list, then 3 shfl_xor butterfly steps merge the 8 partials
// with the (associative, non-commutative) over operator.
__global__ __launch_bounds__(256) void gs_render(
    const float* __restrict__ recs, float* __restrict__ out, int N)
{
    const int t    = threadIdx.x;
    const int c    = t & (SPLIT - 1);                 // chunk index 0..7
    const int pix  = (int)blockIdx.x * (256 / SPLIT) + (t >> 3);
    const float px = (float)(pix & (WIMG - 1));
    const float py = (float)(pix >> 8);

    const int chunkLen = (N + SPLIT - 1) / SPLIT;     // 64 for N=512
    const int g0   = c * chunkLen;
    const int gEnd = min(g0 + chunkLen, N);

    float T = 1.0f, cr = 0.0f, cg = 0.0f, cb = 0.0f;

    #pragma unroll 4
    for (int n = g0; n < gEnd; ++n) {
        const float4* g4 = (const float4*)(recs + n*REC);
        const float4 p0 = g4[0];              // mx, my, A, B
        const float4 p1 = g4[1];              // C, opn, cr, cg
        const float  b8 = recs[n*REC + 8];    // cb

        const float dx = px - p0.x;
        const float dy = py - p0.y;
        const float e2 = fmaf(p0.z, dx*dx, fmaf(p0.w, dx*dy, p1.x*dy*dy));
        const float gau = __builtin_amdgcn_exp2f(e2);
        const float al  = p1.y * gau;
        T *= (1.0f - al);                     // cumprod INCLUDES current term
        const float w = al * T;
        cr = fmaf(w, p1.z, cr);
        cg = fmaf(w, p1.w, cg);
        cb = fmaf(w, b8,  cb);
    }

    // Butterfly merge across the 8 chunk lanes (front-to-back order).
    #pragma unroll
    for (int o = 1; o < SPLIT; o <<= 1) {
        const float Tp = __shfl_xor(T,  o, 64);
        const float rp = __shfl_xor(cr, o, 64);
        const float gp = __shfl_xor(cg, o, 64);
        const float bp = __shfl_xor(cb, o, 64);
        const bool back = (c & o) != 0;       // partner is in front of me
        cr = back ? fmaf(Tp, cr, rp) : fmaf(T, rp, cr);
        cg = back ? fmaf(Tp, cg, gp) : fmaf(T, gp, cg);
        cb = back ? fmaf(Tp, cb, bp) : fmaf(T, bp, cb);
        T *= Tp;
    }

    if (c == 0) {
        const int o = pix * 3;
        out[o+0] = cr;
        out[o+1] = cg;
        out[o+2] = cb;
    }
}

extern "C" void kernel_launch(void* const* d_in, const int* in_sizes, int n_in,
                              void* d_out, int out_size, void* d_ws, size_t ws_size,
                              hipStream_t stream)
{
    const float* means3D = (const float*)d_in[0];
    const float* covs3d  = (const float*)d_in[1];
    const float* colors  = (const float*)d_in[2];
    const float* opac    = (const float*)d_in[3];
    const float* Km      = (const float*)d_in[4];
    const float* Rm      = (const float*)d_in[5];
    const float* tv      = (const float*)d_in[6];
    const int N = in_sizes[3];               // opacities: (N,)

    float* recs = (float*)d_ws;              // N*REC floats = 24 KB
    float* out  = (float*)d_out;

    int preB = ((N + 63) / 64) * 64;
    if (preB > NGMAX) preB = NGMAX;
    gs_preprocess<<<1, preB, 0, stream>>>(means3D, covs3d, colors, opac,
                                          Km, Rm, tv, recs, N);

    const int pixPerBlock = 256 / SPLIT;               // 32
    const int nPix = WIMG * HIMG;
    gs_render<<<dim3(nPix / pixPerBlock), dim3(256), 0, stream>>>(recs, out, N);
}

// Round 3
// 36.696 us; speedup vs baseline: 4.4187x; 4.4187x over previous
//
#include <hip/hip_runtime.h>

// GaussianRenderer: N=512 gaussians -> 256x256x3 f32 image.
// Kernel 1 (1 block): per-gaussian transform + conic + stable depth-rank,
//   writes sorted 12-float records to d_ws.
// Kernel 2: block = 512 threads = 8 waves x 64 pixels. Wave w composites
//   gaussian chunk w with WAVE-UNIFORM record reads (1 cache line per load,
//   scalarizable), 8 waves/SIMD occupancy; 8 partials merged via LDS with the
//   associative over operator.

constexpr int   NGMAX = 1024;   // LDS depth array bound (N=512 here)
constexpr int   REC   = 12;     // floats per sorted gaussian record (48B)
constexpr int   WIMG  = 256;
constexpr int   HIMG  = 256;
constexpr int   SPLIT = 8;      // chunks per pixel chain (= waves per block)
constexpr float LOG2E = 1.4426950408889634f;
constexpr float INV2PI = 0.15915494309189535f;

__global__ __launch_bounds__(NGMAX) void gs_preprocess(
    const float* __restrict__ means3D, const float* __restrict__ covs3d,
    const float* __restrict__ colors,  const float* __restrict__ opac,
    const float* __restrict__ Km,      const float* __restrict__ Rm,
    const float* __restrict__ tvec,    float* __restrict__ recs, int N)
{
    __shared__ float s_depth[NGMAX];
    const int i = threadIdx.x;

    float Kl[9], Rl[9], tl[3];
    #pragma unroll
    for (int k = 0; k < 9; ++k) { Kl[k] = Km[k]; Rl[k] = Rm[k]; }
    tl[0] = tvec[0]; tl[1] = tvec[1]; tl[2] = tvec[2];

    float depth = 3.0e38f;
    float rec[REC];
    if (i < N) {
        const float m0 = means3D[i*3+0], m1 = means3D[i*3+1], m2 = means3D[i*3+2];
        float cam0 = Rl[0]*m0 + Rl[1]*m1 + Rl[2]*m2 + tl[0];
        float cam1 = Rl[3]*m0 + Rl[4]*m1 + Rl[5]*m2 + tl[1];
        float cam2 = Rl[6]*m0 + Rl[7]*m1 + Rl[8]*m2 + tl[2];
        const float Z = cam2;
        depth = fmaxf(Z, 1.0f);

        const float s0 = Kl[0]*cam0 + Kl[1]*cam1 + Kl[2]*cam2;
        const float s1 = Kl[3]*cam0 + Kl[4]*cam1 + Kl[5]*cam2;
        const float s2 = Kl[6]*cam0 + Kl[7]*cam1 + Kl[8]*cam2;
        const float mx = s0 / s2, my = s1 / s2;

        const float fx = Kl[0], fy = Kl[4];
        const float iz = 1.0f / Z;
        float J[2][3];
        J[0][0] = fx*iz; J[0][1] = 0.0f;  J[0][2] = -fx*cam0*iz*iz;
        J[1][0] = 0.0f;  J[1][1] = fy*iz; J[1][2] = -fy*cam1*iz*iz;

        float S[9];
        #pragma unroll
        for (int k = 0; k < 9; ++k) S[k] = covs3d[i*9+k];

        float RS[9], Cc[9];
        #pragma unroll
        for (int r = 0; r < 3; ++r)
            #pragma unroll
            for (int c = 0; c < 3; ++c)
                RS[r*3+c] = Rl[r*3+0]*S[0+c] + Rl[r*3+1]*S[3+c] + Rl[r*3+2]*S[6+c];
        #pragma unroll
        for (int r = 0; r < 3; ++r)
            #pragma unroll
            for (int c = 0; c < 3; ++c)
                Cc[r*3+c] = RS[r*3+0]*Rl[c*3+0] + RS[r*3+1]*Rl[c*3+1] + RS[r*3+2]*Rl[c*3+2];

        float JC[2][3];
        #pragma unroll
        for (int r = 0; r < 2; ++r)
            #pragma unroll
            for (int c = 0; c < 3; ++c)
                JC[r][c] = J[r][0]*Cc[0+c] + J[r][1]*Cc[3+c] + J[r][2]*Cc[6+c];

        const float c200 = JC[0][0]*J[0][0] + JC[0][1]*J[0][1] + JC[0][2]*J[0][2] + 1e-4f;
        const float c201 = JC[0][0]*J[1][0] + JC[0][1]*J[1][1] + JC[0][2]*J[1][2];
        const float c210 = JC[1][0]*J[0][0] + JC[1][1]*J[0][1] + JC[1][2]*J[0][2];
        const float c211 = JC[1][0]*J[1][0] + JC[1][1]*J[1][1] + JC[1][2]*J[1][2] + 1e-4f;

        const float det  = c200*c211 - c201*c210;
        const float idet = 1.0f / det;
        const float ia  = c211*idet;
        const float ibs = -(c201 + c210)*idet;   // inv01+inv10
        const float ic  = c200*idet;

        const bool valid = (depth > 1.0f) && (depth < 50.0f);
        const float nrm  = valid ? (INV2PI / sqrtf(det)) : 0.0f;

        rec[0] = mx;
        rec[1] = my;
        rec[2] = -0.5f*LOG2E*ia;    // A
        rec[3] = -0.5f*LOG2E*ibs;   // B (covers both off-diagonals)
        rec[4] = -0.5f*LOG2E*ic;    // C
        rec[5] = opac[i] * nrm;     // opacity*norm*valid folded
        rec[6] = colors[i*3+0];
        rec[7] = colors[i*3+1];
        rec[8] = colors[i*3+2];
        rec[9] = 0.0f; rec[10] = 0.0f; rec[11] = 0.0f;
    }

    s_depth[i] = depth;
    __syncthreads();

    if (i < N) {
        int rank = 0;
        for (int j = 0; j < N; ++j) {
            const float dj = s_depth[j];
            rank += (dj < depth) || (dj == depth && j < i);
        }
        float4* dst = (float4*)(recs + rank*REC);
        dst[0] = make_float4(rec[0], rec[1], rec[2],  rec[3]);
        dst[1] = make_float4(rec[4], rec[5], rec[6],  rec[7]);
        dst[2] = make_float4(rec[8], rec[9], rec[10], rec[11]);
    }
}

// Block: 512 threads = 8 waves. Wave w = chunk w; lane = pixel (64/block).
// All 64 lanes of a wave read the SAME record -> wave-uniform address ->
// single cache line per load (or s_load). Partials merged via LDS.
__global__ __launch_bounds__(512, 8) void gs_render(
    const float* __restrict__ recs, float* __restrict__ out, int N)
{
    const int t    = threadIdx.x;
    const int w    = t >> 6;                  // wave id = chunk 0..7
    const int lane = t & 63;                  // pixel within block
    const int pix  = (int)blockIdx.x * 64 + lane;
    const float px = (float)(pix & (WIMG - 1));
    const float py = (float)(pix >> 8);       // WIMG == 256

    const int chunkLen = (N + SPLIT - 1) / SPLIT;          // 64 for N=512
    const int g0   = __builtin_amdgcn_readfirstlane(w * chunkLen);
    const int gEnd = min(g0 + chunkLen, N);                // wave-uniform

    float T = 1.0f, cr = 0.0f, cg = 0.0f, cb = 0.0f;

    #pragma unroll 4
    for (int n = g0; n < gEnd; ++n) {
        const float* r = recs + n * REC;      // uniform across the wave
        const float mx = r[0], my = r[1], A = r[2], B = r[3];
        const float C = r[4], opn = r[5];
        const float q0 = r[6], q1 = r[7], q2 = r[8];

        const float dx = px - mx;
        const float dy = py - my;
        const float e2 = fmaf(A, dx*dx, fmaf(B, dx*dy, C*dy*dy));
        const float al = opn * __builtin_amdgcn_exp2f(e2);
        T *= (1.0f - al);                     // cumprod INCLUDES current term
        const float wt = al * T;
        cr = fmaf(wt, q0, cr);
        cg = fmaf(wt, q1, cg);
        cb = fmaf(wt, q2, cb);
    }

    // Merge the 8 chunk-partials per pixel, front-to-back, via LDS.
    __shared__ float4 s_part[SPLIT][64];
    s_part[w][lane] = make_float4(T, cr, cg, cb);
    __syncthreads();

    if (t < 64) {
        float4 f = s_part[0][t];
        float Ta = f.x, r_ = f.y, g_ = f.z, b_ = f.w;
        #pragma unroll
        for (int k = 1; k < SPLIT; ++k) {
            const float4 p = s_part[k][t];
            r_ = fmaf(Ta, p.y, r_);
            g_ = fmaf(Ta, p.z, g_);
            b_ = fmaf(Ta, p.w, b_);
            Ta *= p.x;
        }
        const int o = ((int)blockIdx.x * 64 + t) * 3;
        out[o+0] = r_;
        out[o+1] = g_;
        out[o+2] = b_;
    }
}

extern "C" void kernel_launch(void* const* d_in, const int* in_sizes, int n_in,
                              void* d_out, int out_size, void* d_ws, size_t ws_size,
                              hipStream_t stream)
{
    const float* means3D = (const float*)d_in[0];
    const float* covs3d  = (const float*)d_in[1];
    const float* colors  = (const float*)d_in[2];
    const float* opac    = (const float*)d_in[3];
    const float* Km      = (const float*)d_in[4];
    const float* Rm      = (const float*)d_in[5];
    const float* tv      = (const float*)d_in[6];
    const int N = in_sizes[3];               // opacities: (N,)

    float* recs = (float*)d_ws;              // N*REC floats = 24 KB
    float* out  = (float*)d_out;

    int preB = ((N + 63) / 64) * 64;
    if (preB > NGMAX) preB = NGMAX;
    gs_preprocess<<<1, preB, 0, stream>>>(means3D, covs3d, colors, opac,
                                          Km, Rm, tv, recs, N);

    const int pixPerBlock = 64;
    const int nPix = WIMG * HIMG;
    gs_render<<<dim3(nPix / pixPerBlock), dim3(512), 0, stream>>>(recs, out, N);
}

// Round 4
// 31.112 us; speedup vs baseline: 5.2118x; 1.1795x over previous
//
#include <hip/hip_runtime.h>

// GaussianRenderer: N=512 gaussians -> 256x256x3 f32 image.
// K1 (1 block, 1024 thr): per-gaussian transform + conic + 1e-9 support bbox
//   + stable depth-rank (2-way split count), writes sorted 16-float records.
// K2: block = 512 thr = 8 waves x 64-px row strip. Wave w owns gaussian chunk
//   w (64 gaussians). Lane-parallel bbox-vs-strip test -> __ballot mask ->
//   scalar-driven eval loop over hits only (order preserved). Wave-uniform
//   record reads. 8 partials merged via LDS with the associative over op.

constexpr int   NGMAX = 1024;
constexpr int   REC   = 16;     // floats per sorted record (64B, 4x float4)
constexpr int   WIMG  = 256;
constexpr int   HIMG  = 256;
constexpr int   SPLIT = 8;      // chunks per pixel chain (= waves per block)
constexpr float LOG2E  = 1.4426950408889634f;
constexpr float INV2PI = 0.15915494309189535f;
constexpr float TWOLN2 = 1.3862943611198906f;   // 2*ln(2)
constexpr float LOG2EPS = -29.897352853986263f; // log2(1e-9) cull threshold

__global__ __launch_bounds__(NGMAX) void gs_preprocess(
    const float* __restrict__ means3D, const float* __restrict__ covs3d,
    const float* __restrict__ colors,  const float* __restrict__ opac,
    const float* __restrict__ Km,      const float* __restrict__ Rm,
    const float* __restrict__ tvec,    float* __restrict__ recs, int N)
{
    __shared__ float s_depth[512];
    __shared__ short s_cnt[NGMAX];
    const int i    = threadIdx.x;
    const int g    = i & 511;      // gaussian id
    const int part = i >> 9;       // 0: math + low-half count, 1: high-half count

    float Kl[9], Rl[9], tl[3];
    #pragma unroll
    for (int k = 0; k < 9; ++k) { Kl[k] = Km[k]; Rl[k] = Rm[k]; }
    tl[0] = tvec[0]; tl[1] = tvec[1]; tl[2] = tvec[2];

    float depth = 3.0e38f;
    float rec[13];
    if (part == 0 && g < N) {
        const float m0 = means3D[g*3+0], m1 = means3D[g*3+1], m2 = means3D[g*3+2];
        float cam0 = Rl[0]*m0 + Rl[1]*m1 + Rl[2]*m2 + tl[0];
        float cam1 = Rl[3]*m0 + Rl[4]*m1 + Rl[5]*m2 + tl[1];
        float cam2 = Rl[6]*m0 + Rl[7]*m1 + Rl[8]*m2 + tl[2];
        const float Z = cam2;
        depth = fmaxf(Z, 1.0f);

        const float s0 = Kl[0]*cam0 + Kl[1]*cam1 + Kl[2]*cam2;
        const float s1 = Kl[3]*cam0 + Kl[4]*cam1 + Kl[5]*cam2;
        const float s2 = Kl[6]*cam0 + Kl[7]*cam1 + Kl[8]*cam2;
        const float mx = s0 / s2, my = s1 / s2;

        const float fx = Kl[0], fy = Kl[4];
        const float iz = 1.0f / Z;
        float J[2][3];
        J[0][0] = fx*iz; J[0][1] = 0.0f;  J[0][2] = -fx*cam0*iz*iz;
        J[1][0] = 0.0f;  J[1][1] = fy*iz; J[1][2] = -fy*cam1*iz*iz;

        float S[9];
        #pragma unroll
        for (int k = 0; k < 9; ++k) S[k] = covs3d[g*9+k];

        float RS[9], Cc[9];
        #pragma unroll
        for (int r = 0; r < 3; ++r)
            #pragma unroll
            for (int c = 0; c < 3; ++c)
                RS[r*3+c] = Rl[r*3+0]*S[0+c] + Rl[r*3+1]*S[3+c] + Rl[r*3+2]*S[6+c];
        #pragma unroll
        for (int r = 0; r < 3; ++r)
            #pragma unroll
            for (int c = 0; c < 3; ++c)
                Cc[r*3+c] = RS[r*3+0]*Rl[c*3+0] + RS[r*3+1]*Rl[c*3+1] + RS[r*3+2]*Rl[c*3+2];

        float JC[2][3];
        #pragma unroll
        for (int r = 0; r < 2; ++r)
            #pragma unroll
            for (int c = 0; c < 3; ++c)
                JC[r][c] = J[r][0]*Cc[0+c] + J[r][1]*Cc[3+c] + J[r][2]*Cc[6+c];

        const float c200 = JC[0][0]*J[0][0] + JC[0][1]*J[0][1] + JC[0][2]*J[0][2] + 1e-4f;
        const float c201 = JC[0][0]*J[1][0] + JC[0][1]*J[1][1] + JC[0][2]*J[1][2];
        const float c210 = JC[1][0]*J[0][0] + JC[1][1]*J[0][1] + JC[1][2]*J[0][2];
        const float c211 = JC[1][0]*J[1][0] + JC[1][1]*J[1][1] + JC[1][2]*J[1][2] + 1e-4f;

        const float det  = c200*c211 - c201*c210;
        const float idet = 1.0f / det;
        const float ia  = c211*idet;
        const float ibs = -(c201 + c210)*idet;
        const float ic  = c200*idet;

        const bool  valid = (depth > 1.0f) && (depth < 50.0f);
        const float nrm   = valid ? (INV2PI / sqrtf(det)) : 0.0f;
        const float opn   = opac[g] * nrm;

        // 1e-9 support bbox: ||d||_P <= q0, P^-1 = 2ln2 * Sigma2D
        float x0, x1, y0, y1;
        if (opn > 1e-9f) {
            const float q0 = log2f(opn) - LOG2EPS;      // log2(opn/1e-9) > 0
            const float s  = TWOLN2 * q0;
            const float bx = sqrtf(s * c200);
            const float by = sqrtf(s * c211);
            x0 = mx - bx; x1 = mx + bx;
            y0 = my - by; y1 = my + by;
        } else {
            x0 = 1e30f; x1 = -1e30f; y0 = 1e30f; y1 = -1e30f;  // never hits
        }

        rec[0]  = x0; rec[1] = x1; rec[2] = y0; rec[3] = y1;
        rec[4]  = mx; rec[5] = my;
        rec[6]  = -0.5f*LOG2E*ia;    // A
        rec[7]  = -0.5f*LOG2E*ibs;   // B
        rec[8]  = -0.5f*LOG2E*ic;    // C
        rec[9]  = opn;
        rec[10] = colors[g*3+0];
        rec[11] = colors[g*3+1];
        rec[12] = colors[g*3+2];
    }

    if (part == 0) s_depth[g] = depth;   // +inf pad for g >= N
    __syncthreads();

    // 2-way split stable rank count: thread (g,part) counts half the array.
    const float dg = s_depth[g];
    const int   j0 = part ? 256 : 0;
    int cnt = 0;
    #pragma unroll 8
    for (int j = j0; j < j0 + 256; ++j) {
        const float dj = s_depth[j];
        cnt += (dj < dg) || (dj == dg && j < g);
    }
    s_cnt[i] = (short)cnt;
    __syncthreads();

    if (part == 0 && g < N) {
        const int rank = (int)s_cnt[g] + (int)s_cnt[g + 512];
        float4* dst = (float4*)(recs + rank*REC);
        dst[0] = make_float4(rec[0],  rec[1],  rec[2],  rec[3]);
        dst[1] = make_float4(rec[4],  rec[5],  rec[6],  rec[7]);
        dst[2] = make_float4(rec[8],  rec[9],  rec[10], rec[11]);
        dst[3] = make_float4(rec[12], 0.0f,    0.0f,    0.0f);
    }
}

// Block: 512 threads = 8 waves; block covers a 64x1 pixel strip.
// Wave w = gaussian chunk w. Lane-parallel bbox test -> ballot mask ->
// scalar-driven eval loop over hits (uniform record reads).
__global__ __launch_bounds__(512, 8) void gs_render(
    const float* __restrict__ recs, float* __restrict__ out, int N)
{
    const int t    = threadIdx.x;
    const int w    = t >> 6;
    const int lane = t & 63;
    const int pix  = (int)blockIdx.x * 64 + lane;
    const float px  = (float)(pix & (WIMG - 1));
    const float pyf = (float)(pix >> 8);                     // row of strip
    const float sx0 = (float)(((int)blockIdx.x & 3) * 64);   // strip x range
    const float sx1 = sx0 + 63.0f;

    const int chunkLen = (N + SPLIT - 1) / SPLIT;            // 64 for N=512
    const int g0   = w * chunkLen;
    const int gEnd = min(g0 + chunkLen, N);

    float T = 1.0f, cr = 0.0f, cg = 0.0f, cb = 0.0f;

    for (int base = g0; base < gEnd; base += 64) {
        // lane-parallel test: lane l tests gaussian base+l vs this strip
        bool hit = false;
        const int gi = base + lane;
        if (gi < gEnd) {
            const float4 bb = *(const float4*)(recs + gi*REC); // x0,x1,y0,y1
            hit = !(bb.y < sx0 || bb.x > sx1 || bb.w < pyf || bb.z > pyf);
        }
        unsigned long long mask = __ballot(hit);

        while (mask) {
            const int k = __builtin_ctzll(mask);
            mask &= mask - 1;
            const float* r = recs + (base + k)*REC;   // wave-uniform
            const float4 p1 = *(const float4*)(r + 4);  // mx,my,A,B
            const float4 p2 = *(const float4*)(r + 8);  // C,opn,cr,cg
            const float  cbl = r[12];

            const float dx = px  - p1.x;
            const float dy = pyf - p1.y;
            const float e2 = fmaf(p1.z, dx*dx, fmaf(p1.w, dx*dy, p2.x*dy*dy));
            const float al = p2.y * __builtin_amdgcn_exp2f(e2);
            T *= (1.0f - al);                 // cumprod INCLUDES current term
            const float wt = al * T;
            cr = fmaf(wt, p2.z, cr);
            cg = fmaf(wt, p2.w, cg);
            cb = fmaf(wt, cbl, cb);
        }
    }

    // Merge the 8 chunk-partials per pixel, front-to-back, via LDS.
    __shared__ float4 s_part[SPLIT][64];
    s_part[w][lane] = make_float4(T, cr, cg, cb);
    __syncthreads();

    if (t < 64) {
        float4 f = s_part[0][t];
        float Ta = f.x, r_ = f.y, g_ = f.z, b_ = f.w;
        #pragma unroll
        for (int k = 1; k < SPLIT; ++k) {
            const float4 p = s_part[k][t];
            r_ = fmaf(Ta, p.y, r_);
            g_ = fmaf(Ta, p.z, g_);
            b_ = fmaf(Ta, p.w, b_);
            Ta *= p.x;
        }
        const int o = ((int)blockIdx.x * 64 + t) * 3;
        out[o+0] = r_;
        out[o+1] = g_;
        out[o+2] = b_;
    }
}

extern "C" void kernel_launch(void* const* d_in, const int* in_sizes, int n_in,
                              void* d_out, int out_size, void* d_ws, size_t ws_size,
                              hipStream_t stream)
{
    const float* means3D = (const float*)d_in[0];
    const float* covs3d  = (const float*)d_in[1];
    const float* colors  = (const float*)d_in[2];
    const float* opac    = (const float*)d_in[3];
    const float* Km      = (const float*)d_in[4];
    const float* Rm      = (const float*)d_in[5];
    const float* tv      = (const float*)d_in[6];
    const int N = in_sizes[3];               // opacities: (N,)

    float* recs = (float*)d_ws;              // N*REC floats = 32 KB
    float* out  = (float*)d_out;

    gs_preprocess<<<1, NGMAX, 0, stream>>>(means3D, covs3d, colors, opac,
                                           Km, Rm, tv, recs, N);

    const int nPix = WIMG * HIMG;
    gs_render<<<dim3(nPix / 64), dim3(512), 0, stream>>>(recs, out, N);
}

// Round 5
// 17.466 us; speedup vs baseline: 9.2838x; 1.7813x over previous
//
#include <hip/hip_runtime.h>

// GaussianRenderer: N=512 gaussians -> 256x256x3 f32 image.
// K1 (8 blocks x 512 thr): every block computes all 512 depths (3 fma each);
//   block b does heavy math for its 64 gaussians (1 thr each) while all 8
//   waves compute 8-way-split stable rank partials; writes sorted 16-float
//   records (bbox + conic + color) to d_ws.
// K2 (1024 blocks x 512 thr): 64-px row strip per block. Stage all records
//   into LDS (SoA bbox + 48B eval rows). Wave w owns gaussian chunk w:
//   lane-parallel bbox test -> ballot -> broadcast-LDS eval of hits only.
//   8 chunk partials merged with the associative over operator.

constexpr int   REC   = 16;     // floats per sorted record (64B)
constexpr int   WIMG  = 256;
constexpr int   HIMG  = 256;
constexpr int   SPLIT = 8;
constexpr float LOG2E  = 1.4426950408889634f;
constexpr float INV2PI = 0.15915494309189535f;
constexpr float TWOLN2 = 1.3862943611198906f;   // 2*ln(2)
constexpr float LOG2EPS = -29.897352853986263f; // log2(1e-9) cull threshold

__global__ __launch_bounds__(512) void gs_preprocess(
    const float* __restrict__ means3D, const float* __restrict__ covs3d,
    const float* __restrict__ colors,  const float* __restrict__ opac,
    const float* __restrict__ Km,      const float* __restrict__ Rm,
    const float* __restrict__ tvec,    float* __restrict__ recs, int N)
{
    __shared__ float s_depth[512];
    __shared__ int   s_cnt[64][9];          // [gaussian][partial], padded
    const int t  = threadIdx.x;
    const int l  = t & 63, p = t >> 6;
    const int gi = (int)blockIdx.x * 64 + l;

    // Phase A: all threads -> depth of slot t (pad +inf)
    float d_all = 3.0e38f;
    if (t < N) {
        const float m0 = means3D[t*3+0], m1 = means3D[t*3+1], m2 = means3D[t*3+2];
        d_all = fmaxf(Rm[6]*m0 + Rm[7]*m1 + Rm[8]*m2 + tvec[2], 1.0f);
    }
    s_depth[t] = d_all;
    __syncthreads();

    // Phase B: 8-way split stable rank partial for gaussian gi
    const float dg = s_depth[gi & 511];
    int cnt = 0;
    #pragma unroll 16
    for (int j = p*64; j < p*64 + 64; ++j) {
        const float dj = s_depth[j];
        cnt += (dj < dg) || (dj == dg && j < gi);
    }
    s_cnt[l][p] = cnt;

    // Phase C: heavy per-gaussian math on p==0 threads (runs while other
    // waves finish their rank partials)
    float rec[13];
    const bool act = (p == 0) && (gi < N);
    if (act) {
        float Kl[9], Rl[9], tl[3];
        #pragma unroll
        for (int k = 0; k < 9; ++k) { Kl[k] = Km[k]; Rl[k] = Rm[k]; }
        tl[0] = tvec[0]; tl[1] = tvec[1]; tl[2] = tvec[2];

        const float m0 = means3D[gi*3+0], m1 = means3D[gi*3+1], m2 = means3D[gi*3+2];
        const float cam0 = Rl[0]*m0 + Rl[1]*m1 + Rl[2]*m2 + tl[0];
        const float cam1 = Rl[3]*m0 + Rl[4]*m1 + Rl[5]*m2 + tl[1];
        const float cam2 = Rl[6]*m0 + Rl[7]*m1 + Rl[8]*m2 + tl[2];
        const float Z = cam2;
        const float depth = fmaxf(Z, 1.0f);

        const float s0 = Kl[0]*cam0 + Kl[1]*cam1 + Kl[2]*cam2;
        const float s1 = Kl[3]*cam0 + Kl[4]*cam1 + Kl[5]*cam2;
        const float s2 = Kl[6]*cam0 + Kl[7]*cam1 + Kl[8]*cam2;
        const float mx = s0 / s2, my = s1 / s2;

        const float fx = Kl[0], fy = Kl[4];
        const float iz = 1.0f / Z;
        float J[2][3];
        J[0][0] = fx*iz; J[0][1] = 0.0f;  J[0][2] = -fx*cam0*iz*iz;
        J[1][0] = 0.0f;  J[1][1] = fy*iz; J[1][2] = -fy*cam1*iz*iz;

        float S[9];
        #pragma unroll
        for (int k = 0; k < 9; ++k) S[k] = covs3d[gi*9+k];

        float RS[9], Cc[9];
        #pragma unroll
        for (int r = 0; r < 3; ++r)
            #pragma unroll
            for (int c = 0; c < 3; ++c)
                RS[r*3+c] = Rl[r*3+0]*S[0+c] + Rl[r*3+1]*S[3+c] + Rl[r*3+2]*S[6+c];
        #pragma unroll
        for (int r = 0; r < 3; ++r)
            #pragma unroll
            for (int c = 0; c < 3; ++c)
                Cc[r*3+c] = RS[r*3+0]*Rl[c*3+0] + RS[r*3+1]*Rl[c*3+1] + RS[r*3+2]*Rl[c*3+2];

        float JC[2][3];
        #pragma unroll
        for (int r = 0; r < 2; ++r)
            #pragma unroll
            for (int c = 0; c < 3; ++c)
                JC[r][c] = J[r][0]*Cc[0+c] + J[r][1]*Cc[3+c] + J[r][2]*Cc[6+c];

        const float c200 = JC[0][0]*J[0][0] + JC[0][1]*J[0][1] + JC[0][2]*J[0][2] + 1e-4f;
        const float c201 = JC[0][0]*J[1][0] + JC[0][1]*J[1][1] + JC[0][2]*J[1][2];
        const float c210 = JC[1][0]*J[0][0] + JC[1][1]*J[0][1] + JC[1][2]*J[0][2];
        const float c211 = JC[1][0]*J[1][0] + JC[1][1]*J[1][1] + JC[1][2]*J[1][2] + 1e-4f;

        const float det  = c200*c211 - c201*c210;
        const float idet = 1.0f / det;
        const float ia  = c211*idet;
        const float ibs = -(c201 + c210)*idet;
        const float ic  = c200*idet;

        const bool  valid = (depth > 1.0f) && (depth < 50.0f);
        const float nrm   = valid ? (INV2PI / sqrtf(det)) : 0.0f;
        const float opn   = opac[gi] * nrm;

        float x0, x1, y0, y1;
        if (opn > 1e-9f) {
            const float q0 = log2f(opn) - LOG2EPS;      // log2(opn/1e-9)
            const float s  = TWOLN2 * q0;
            const float bx = sqrtf(s * c200);
            const float by = sqrtf(s * c211);
            x0 = mx - bx; x1 = mx + bx;
            y0 = my - by; y1 = my + by;
        } else {
            x0 = 1e30f; x1 = -1e30f; y0 = 1e30f; y1 = -1e30f;
        }

        rec[0]  = x0; rec[1] = x1; rec[2] = y0; rec[3] = y1;
        rec[4]  = mx; rec[5] = my;
        rec[6]  = -0.5f*LOG2E*ia;
        rec[7]  = -0.5f*LOG2E*ibs;
        rec[8]  = -0.5f*LOG2E*ic;
        rec[9]  = opn;
        rec[10] = colors[gi*3+0];
        rec[11] = colors[gi*3+1];
        rec[12] = colors[gi*3+2];
    }
    __syncthreads();

    if (act) {
        int rank = 0;
        #pragma unroll
        for (int q = 0; q < 8; ++q) rank += s_cnt[l][q];
        float4* dst = (float4*)(recs + rank*REC);
        dst[0] = make_float4(rec[0],  rec[1],  rec[2],  rec[3]);
        dst[1] = make_float4(rec[4],  rec[5],  rec[6],  rec[7]);
        dst[2] = make_float4(rec[8],  rec[9],  rec[10], rec[11]);
        dst[3] = make_float4(rec[12], 0.0f,    0.0f,    0.0f);
    }
}

// Block: 512 thr = 8 waves; 64x1 pixel row strip. All records LDS-staged.
__global__ __launch_bounds__(512, 8) void gs_render(
    const float* __restrict__ recs, float* __restrict__ out, int N)
{
    __shared__ float  s_bb0[512], s_bb1[512], s_bb2[512], s_bb3[512];
    __shared__ float  s_ev[512][12];          // 48B rows (16B-aligned)
    __shared__ float4 s_part[SPLIT][64];

    const int t = threadIdx.x;

    // Stage: thread t handles record t. Pads never hit.
    if (t < N) {
        const float4 a = *(const float4*)(recs + t*REC + 0);   // bbox
        const float4 b = *(const float4*)(recs + t*REC + 4);   // mx,my,A,B
        const float4 c = *(const float4*)(recs + t*REC + 8);   // C,opn,cr,cg
        const float4 d = *(const float4*)(recs + t*REC + 12);  // cb,-,-,-
        s_bb0[t] = a.x; s_bb1[t] = a.y; s_bb2[t] = a.z; s_bb3[t] = a.w;
        s_ev[t][0] = b.x; s_ev[t][1] = b.y; s_ev[t][2] = b.z; s_ev[t][3] = b.w;
        s_ev[t][4] = c.x; s_ev[t][5] = c.y; s_ev[t][6] = c.z; s_ev[t][7] = c.w;
        s_ev[t][8] = d.x;
    } else {
        s_bb0[t] = 1e30f; s_bb1[t] = -1e30f; s_bb2[t] = 1e30f; s_bb3[t] = -1e30f;
    }
    __syncthreads();

    const int w    = t >> 6;
    const int lane = t & 63;
    const float sx0 = (float)(((int)blockIdx.x & 3) * 64);
    const float sx1 = sx0 + 63.0f;
    const float px  = sx0 + (float)lane;
    const float py  = (float)((int)blockIdx.x >> 2);   // uniform per block

    // Lane-parallel bbox test for chunk w (64 gaussians), then ballot.
    const int base = w * 64;
    bool hit;
    {
        const float x0 = s_bb0[base+lane], x1 = s_bb1[base+lane];
        const float y0 = s_bb2[base+lane], y1 = s_bb3[base+lane];
        hit = !(x1 < sx0 || x0 > sx1 || y1 < py || y0 > py);
    }
    unsigned long long mask = __ballot(hit);

    float T = 1.0f, cr = 0.0f, cg = 0.0f, cb = 0.0f;
    while (mask) {
        const int k = __builtin_ctzll(mask);
        mask &= mask - 1;
        const float* e = s_ev[base + k];      // wave-uniform -> broadcast
        const float dx = px - e[0];
        const float dy = py - e[1];
        const float e2 = fmaf(e[2], dx*dx, fmaf(e[3], dx*dy, e[4]*dy*dy));
        const float al = e[5] * __builtin_amdgcn_exp2f(e2);
        T *= (1.0f - al);                     // cumprod INCLUDES current term
        const float wt = al * T;
        cr = fmaf(wt, e[6], cr);
        cg = fmaf(wt, e[7], cg);
        cb = fmaf(wt, e[8], cb);
    }

    s_part[w][lane] = make_float4(T, cr, cg, cb);
    __syncthreads();

    if (t < 64) {
        float4 f = s_part[0][t];
        float Ta = f.x, r_ = f.y, g_ = f.z, b_ = f.w;
        #pragma unroll
        for (int k = 1; k < SPLIT; ++k) {
            const float4 p = s_part[k][t];
            r_ = fmaf(Ta, p.y, r_);
            g_ = fmaf(Ta, p.z, g_);
            b_ = fmaf(Ta, p.w, b_);
            Ta *= p.x;
        }
        const int o = ((int)blockIdx.x * 64 + t) * 3;
        out[o+0] = r_;
        out[o+1] = g_;
        out[o+2] = b_;
    }
}

extern "C" void kernel_launch(void* const* d_in, const int* in_sizes, int n_in,
                              void* d_out, int out_size, void* d_ws, size_t ws_size,
                              hipStream_t stream)
{
    const float* means3D = (const float*)d_in[0];
    const float* covs3d  = (const float*)d_in[1];
    const float* colors  = (const float*)d_in[2];
    const float* opac    = (const float*)d_in[3];
    const float* Km      = (const float*)d_in[4];
    const float* Rm      = (const float*)d_in[5];
    const float* tv      = (const float*)d_in[6];
    const int N = in_sizes[3];               // opacities: (N,)

    float* recs = (float*)d_ws;              // N*REC floats = 32 KB
    float* out  = (float*)d_out;

    gs_preprocess<<<dim3((N + 63) / 64), dim3(512), 0, stream>>>(
        means3D, covs3d, colors, opac, Km, Rm, tv, recs, N);

    gs_render<<<dim3(WIMG * HIMG / 64), dim3(512), 0, stream>>>(recs, out, N);
}

// Round 6
// 16.111 us; speedup vs baseline: 10.0647x; 1.0841x over previous
//
#include <hip/hip_runtime.h>

// GaussianRenderer: N=512 gaussians -> 256x256x3 f32 image.
// K1 (8 blocks x 512 thr): depths (all) + heavy math (wave 0, 1 thr/gaussian)
//   + 8-way-split stable rank; writes sorted 16-float records:
//   [my,c2,L2,c1] [mx,p00,A,B] [C,opn,r,g] [b,-,-,-]
//   where alpha>=eps  <=>  p00*(dx+c1*dy)^2 + c2*dy^2 <= L2  (eps=1e-7).
// K2 (1024 blocks x 512 thr): 64x1 row strip per block. Stage records to LDS
//   (SoA test params + 48B eval rows). Wave w owns chunk w: lane-parallel
//   EXACT ellipse-vs-strip test -> ballot -> broadcast-LDS eval of hits.
//   8 chunk partials merged with the associative over op; coalesced store.

constexpr int   REC   = 16;     // floats per sorted record (64B)
constexpr int   WIMG  = 256;
constexpr int   HIMG  = 256;
constexpr int   SPLIT = 8;
constexpr float LOG2E  = 1.4426950408889634f;
constexpr float INV2PI = 0.15915494309189535f;
constexpr float INVEPS = 1.0e7f;                // 1/eps, eps = 1e-7 cull

__global__ __launch_bounds__(512) void gs_preprocess(
    const float* __restrict__ means3D, const float* __restrict__ covs3d,
    const float* __restrict__ colors,  const float* __restrict__ opac,
    const float* __restrict__ Km,      const float* __restrict__ Rm,
    const float* __restrict__ tvec,    float* __restrict__ recs, int N)
{
    __shared__ float s_depth[512];
    __shared__ int   s_cnt[64][9];          // [gaussian][partial], padded
    const int t  = threadIdx.x;
    const int l  = t & 63, p = t >> 6;
    const int gi = (int)blockIdx.x * 64 + l;

    // Phase A: all threads -> depth of slot t (pad +inf)
    float d_all = 3.0e38f;
    if (t < N) {
        const float m0 = means3D[t*3+0], m1 = means3D[t*3+1], m2 = means3D[t*3+2];
        d_all = fmaxf(Rm[6]*m0 + Rm[7]*m1 + Rm[8]*m2 + tvec[2], 1.0f);
    }
    s_depth[t] = d_all;
    __syncthreads();

    // Phase B: 8-way split stable rank partial for gaussian gi
    const float dg = s_depth[gi & 511];
    int cnt = 0;
    #pragma unroll 16
    for (int j = p*64; j < p*64 + 64; ++j) {
        const float dj = s_depth[j];
        cnt += (dj < dg) || (dj == dg && j < gi);
    }
    s_cnt[l][p] = cnt;

    // Phase C: heavy per-gaussian math on p==0 threads
    float rec[13];
    const bool act = (p == 0) && (gi < N);
    if (act) {
        float Kl[9], Rl[9], tl[3];
        #pragma unroll
        for (int k = 0; k < 9; ++k) { Kl[k] = Km[k]; Rl[k] = Rm[k]; }
        tl[0] = tvec[0]; tl[1] = tvec[1]; tl[2] = tvec[2];

        const float m0 = means3D[gi*3+0], m1 = means3D[gi*3+1], m2 = means3D[gi*3+2];
        const float cam0 = Rl[0]*m0 + Rl[1]*m1 + Rl[2]*m2 + tl[0];
        const float cam1 = Rl[3]*m0 + Rl[4]*m1 + Rl[5]*m2 + tl[1];
        const float cam2 = Rl[6]*m0 + Rl[7]*m1 + Rl[8]*m2 + tl[2];
        const float Z = cam2;
        const float depth = fmaxf(Z, 1.0f);

        const float s0 = Kl[0]*cam0 + Kl[1]*cam1 + Kl[2]*cam2;
        const float s1 = Kl[3]*cam0 + Kl[4]*cam1 + Kl[5]*cam2;
        const float s2 = Kl[6]*cam0 + Kl[7]*cam1 + Kl[8]*cam2;
        const float mx = s0 / s2, my = s1 / s2;

        const float fx = Kl[0], fy = Kl[4];
        const float iz = 1.0f / Z;
        float J[2][3];
        J[0][0] = fx*iz; J[0][1] = 0.0f;  J[0][2] = -fx*cam0*iz*iz;
        J[1][0] = 0.0f;  J[1][1] = fy*iz; J[1][2] = -fy*cam1*iz*iz;

        float S[9];
        #pragma unroll
        for (int k = 0; k < 9; ++k) S[k] = covs3d[gi*9+k];

        float RS[9], Cc[9];
        #pragma unroll
        for (int r = 0; r < 3; ++r)
            #pragma unroll
            for (int c = 0; c < 3; ++c)
                RS[r*3+c] = Rl[r*3+0]*S[0+c] + Rl[r*3+1]*S[3+c] + Rl[r*3+2]*S[6+c];
        #pragma unroll
        for (int r = 0; r < 3; ++r)
            #pragma unroll
            for (int c = 0; c < 3; ++c)
                Cc[r*3+c] = RS[r*3+0]*Rl[c*3+0] + RS[r*3+1]*Rl[c*3+1] + RS[r*3+2]*Rl[c*3+2];

        float JC[2][3];
        #pragma unroll
        for (int r = 0; r < 2; ++r)
            #pragma unroll
            for (int c = 0; c < 3; ++c)
                JC[r][c] = J[r][0]*Cc[0+c] + J[r][1]*Cc[3+c] + J[r][2]*Cc[6+c];

        const float c200 = JC[0][0]*J[0][0] + JC[0][1]*J[0][1] + JC[0][2]*J[0][2] + 1e-4f;
        const float c201 = JC[0][0]*J[1][0] + JC[0][1]*J[1][1] + JC[0][2]*J[1][2];
        const float c210 = JC[1][0]*J[0][0] + JC[1][1]*J[0][1] + JC[1][2]*J[0][2];
        const float c211 = JC[1][0]*J[1][0] + JC[1][1]*J[1][1] + JC[1][2]*J[1][2] + 1e-4f;

        const float det  = c200*c211 - c201*c210;
        const float idet = 1.0f / det;
        const float ia   = c211*idet;                    // P00
        const float i01  = -0.5f*(c201 + c210)*idet;     // P01 (symmetrized)
        const float ic   = c200*idet;                    // P11
        const float ibs  = 2.0f*i01;                     // matches old B def

        const bool  valid = (depth > 1.0f) && (depth < 50.0f);
        const float nrm   = valid ? (INV2PI / sqrtf(det)) : 0.0f;
        const float opn   = opac[gi] * nrm;

        // Exact support test params: Q = ia*(dx+c1*dy)^2 + c2*dy^2 <= L2
        const float c1 = i01 / ia;
        const float c2 = ic - i01*i01/ia;
        const float L2 = 2.0f * logf(opn * INVEPS);      // opn<=0 -> -inf

        rec[0]  = my;  rec[1] = c2;  rec[2] = L2;  rec[3] = c1;
        rec[4]  = mx;  rec[5] = ia;
        rec[6]  = -0.5f*LOG2E*ia;    // A
        rec[7]  = -0.5f*LOG2E*ibs;   // B
        rec[8]  = -0.5f*LOG2E*ic;    // C
        rec[9]  = opn;
        rec[10] = colors[gi*3+0];
        rec[11] = colors[gi*3+1];
        rec[12] = colors[gi*3+2];
    }
    __syncthreads();

    if (act) {
        int rank = 0;
        #pragma unroll
        for (int q = 0; q < 8; ++q) rank += s_cnt[l][q];
        float4* dst = (float4*)(recs + rank*REC);
        dst[0] = make_float4(rec[0],  rec[1],  rec[2],  rec[3]);
        dst[1] = make_float4(rec[4],  rec[5],  rec[6],  rec[7]);
        dst[2] = make_float4(rec[8],  rec[9],  rec[10], rec[11]);
        dst[3] = make_float4(rec[12], 0.0f,    0.0f,    0.0f);
    }
}

// Block: 512 thr = 8 waves; 64x1 pixel row strip. Records LDS-staged.
__global__ __launch_bounds__(512, 8) void gs_render(
    const float* __restrict__ recs, float* __restrict__ out, int N)
{
    __shared__ float  s_my[512], s_c2[512], s_L2[512], s_c1[512], s_mx[512], s_p0[512];
    __shared__ float  s_ev[512][12];          // 48B rows (16B-aligned)
    __shared__ float4 s_part[SPLIT][64];
    __shared__ float  s_rgb[192];

    const int t = threadIdx.x;

    // Stage: thread t handles record t.
    if (t < N) {
        const float4 a = *(const float4*)(recs + t*REC + 0);   // my,c2,L2,c1
        const float4 b = *(const float4*)(recs + t*REC + 4);   // mx,p00,A,B
        const float4 c = *(const float4*)(recs + t*REC + 8);   // C,opn,r,g
        const float4 d = *(const float4*)(recs + t*REC + 12);  // b,-,-,-
        s_my[t] = a.x; s_c2[t] = a.y; s_L2[t] = a.z; s_c1[t] = a.w;
        s_mx[t] = b.x; s_p0[t] = b.y;
        float4* ev = (float4*)s_ev[t];
        ev[0] = make_float4(b.x, a.x, b.z, b.w);   // mx, my, A, B
        ev[1] = make_float4(c.x, c.y, c.z, c.w);   // C, opn, r, g
        s_ev[t][8] = d.x;                          // blue
    } else {
        s_my[t] = 0.0f; s_c2[t] = 0.0f; s_L2[t] = -1e30f;
        s_c1[t] = 0.0f; s_mx[t] = 0.0f; s_p0[t] = 1.0f;
    }
    __syncthreads();

    const int w    = t >> 6;
    const int lane = t & 63;
    const float sx0 = (float)(((int)blockIdx.x & 3) * 64);
    const float scx = sx0 + 31.5f;                     // strip center x
    const float px  = sx0 + (float)lane;
    const float py  = (float)((int)blockIdx.x >> 2);   // uniform per block

    // Lane-parallel EXACT ellipse-vs-strip test for chunk w, then ballot.
    const int base = w * 64;
    bool hit;
    {
        const int j = base + lane;
        const float dy  = py - s_my[j];
        const float rem = fmaf(-s_c2[j], dy*dy, s_L2[j]);
        const float xc  = fmaf(-s_c1[j], dy, s_mx[j]);
        const float t1  = fmaxf(fabsf(xc - scx) - 31.5f, 0.0f);
        hit = (s_p0[j]*t1*t1 <= rem);      // t1=0 -> rem>=0 test
    }
    unsigned long long mask = __ballot(hit);

    float T = 1.0f, cr = 0.0f, cg = 0.0f, cb = 0.0f;
    while (mask) {
        const int k = __builtin_ctzll(mask);
        mask &= mask - 1;
        const float* e = s_ev[base + k];      // wave-uniform -> broadcast
        const float4 v0 = *(const float4*)(e + 0);   // mx,my,A,B
        const float4 v1 = *(const float4*)(e + 4);   // C,opn,r,g
        const float  bl = e[8];
        const float dx = px - v0.x;
        const float dy = py - v0.y;
        const float e2 = fmaf(v0.z, dx*dx, fmaf(v0.w, dx*dy, v1.x*dy*dy));
        const float al = v1.y * __builtin_amdgcn_exp2f(e2);
        T *= (1.0f - al);                     // cumprod INCLUDES current term
        const float wt = al * T;
        cr = fmaf(wt, v1.z, cr);
        cg = fmaf(wt, v1.w, cg);
        cb = fmaf(wt, bl,  cb);
    }

    s_part[w][lane] = make_float4(T, cr, cg, cb);
    __syncthreads();

    if (t < 64) {
        float4 f = s_part[0][t];
        float Ta = f.x, r_ = f.y, g_ = f.z, b_ = f.w;
        #pragma unroll
        for (int k = 1; k < SPLIT; ++k) {
            const float4 p = s_part[k][t];
            r_ = fmaf(Ta, p.y, r_);
            g_ = fmaf(Ta, p.z, g_);
            b_ = fmaf(Ta, p.w, b_);
            Ta *= p.x;
        }
        s_rgb[t*3+0] = r_;
        s_rgb[t*3+1] = g_;
        s_rgb[t*3+2] = b_;
    }
    __syncthreads();

    if (t < 192) {
        out[(int)blockIdx.x * 192 + t] = s_rgb[t];   // coalesced
    }
}

extern "C" void kernel_launch(void* const* d_in, const int* in_sizes, int n_in,
                              void* d_out, int out_size, void* d_ws, size_t ws_size,
                              hipStream_t stream)
{
    const float* means3D = (const float*)d_in[0];
    const float* covs3d  = (const float*)d_in[1];
    const float* colors  = (const float*)d_in[2];
    const float* opac    = (const float*)d_in[3];
    const float* Km      = (const float*)d_in[4];
    const float* Rm      = (const float*)d_in[5];
    const float* tv      = (const float*)d_in[6];
    const int N = in_sizes[3];               // opacities: (N,)

    float* recs = (float*)d_ws;              // N*REC floats = 32 KB
    float* out  = (float*)d_out;

    gs_preprocess<<<dim3((N + 63) / 64), dim3(512), 0, stream>>>(
        means3D, covs3d, colors, opac, Km, Rm, tv, recs, N);

    gs_render<<<dim3(WIMG * HIMG / 64), dim3(512), 0, stream>>>(recs, out, N);
}

// Round 7
// 15.780 us; speedup vs baseline: 10.2756x; 1.0210x over previous
//
#include <hip/hip_runtime.h>

// GaussianRenderer: N=512 gaussians -> 256x256x3 f32 image.
// K1 (8 blocks x 512 thr): depths (all) + heavy math (wave 0, 1 thr/gaussian)
//   + 8-way-split stable rank; writes sorted 16-float records:
//   [my,c2,L2,c1] [mx,p00,A,B] [C,opn,r,g] [b,-,-,-]
//   where alpha>=eps  <=>  p00*(dx+c1*dy)^2 + c2*dy^2 <= L2  (eps=1e-7).
// K2 (512 blocks x 512 thr): 64x2 row-pair tile per block. Stage records to
//   LDS once; wave w owns chunk w: exact ellipse test vs {row0,row1} ->
//   ballot -> COMPACTED hit list -> pipelined broadcast-LDS eval feeding
//   BOTH rows (shared dx/loads, 2 independent T-chains). 8 chunk partials
//   per row merged with the associative over op; coalesced store.

constexpr int   REC   = 16;     // floats per sorted record (64B)
constexpr int   WIMG  = 256;
constexpr int   HIMG  = 256;
constexpr int   SPLIT = 8;
constexpr float LOG2E  = 1.4426950408889634f;
constexpr float INV2PI = 0.15915494309189535f;
constexpr float INVEPS = 1.0e7f;                // 1/eps, eps = 1e-7 cull

__global__ __launch_bounds__(512) void gs_preprocess(
    const float* __restrict__ means3D, const float* __restrict__ covs3d,
    const float* __restrict__ colors,  const float* __restrict__ opac,
    const float* __restrict__ Km,      const float* __restrict__ Rm,
    const float* __restrict__ tvec,    float* __restrict__ recs, int N)
{
    __shared__ float s_depth[512];
    __shared__ int   s_cnt[64][9];          // [gaussian][partial], padded
    const int t  = threadIdx.x;
    const int l  = t & 63, p = t >> 6;
    const int gi = (int)blockIdx.x * 64 + l;

    // Phase A: all threads -> depth of slot t (pad +inf)
    float d_all = 3.0e38f;
    if (t < N) {
        const float m0 = means3D[t*3+0], m1 = means3D[t*3+1], m2 = means3D[t*3+2];
        d_all = fmaxf(Rm[6]*m0 + Rm[7]*m1 + Rm[8]*m2 + tvec[2], 1.0f);
    }
    s_depth[t] = d_all;
    __syncthreads();

    // Phase B: 8-way split stable rank partial for gaussian gi
    const float dg = s_depth[gi & 511];
    int cnt = 0;
    #pragma unroll 16
    for (int j = p*64; j < p*64 + 64; ++j) {
        const float dj = s_depth[j];
        cnt += (dj < dg) || (dj == dg && j < gi);
    }
    s_cnt[l][p] = cnt;

    // Phase C: heavy per-gaussian math on p==0 threads
    float rec[13];
    const bool act = (p == 0) && (gi < N);
    if (act) {
        float Kl[9], Rl[9], tl[3];
        #pragma unroll
        for (int k = 0; k < 9; ++k) { Kl[k] = Km[k]; Rl[k] = Rm[k]; }
        tl[0] = tvec[0]; tl[1] = tvec[1]; tl[2] = tvec[2];

        const float m0 = means3D[gi*3+0], m1 = means3D[gi*3+1], m2 = means3D[gi*3+2];
        const float cam0 = Rl[0]*m0 + Rl[1]*m1 + Rl[2]*m2 + tl[0];
        const float cam1 = Rl[3]*m0 + Rl[4]*m1 + Rl[5]*m2 + tl[1];
        const float cam2 = Rl[6]*m0 + Rl[7]*m1 + Rl[8]*m2 + tl[2];
        const float Z = cam2;
        const float depth = fmaxf(Z, 1.0f);

        const float s0 = Kl[0]*cam0 + Kl[1]*cam1 + Kl[2]*cam2;
        const float s1 = Kl[3]*cam0 + Kl[4]*cam1 + Kl[5]*cam2;
        const float s2 = Kl[6]*cam0 + Kl[7]*cam1 + Kl[8]*cam2;
        const float mx = s0 / s2, my = s1 / s2;

        const float fx = Kl[0], fy = Kl[4];
        const float iz = 1.0f / Z;
        float J[2][3];
        J[0][0] = fx*iz; J[0][1] = 0.0f;  J[0][2] = -fx*cam0*iz*iz;
        J[1][0] = 0.0f;  J[1][1] = fy*iz; J[1][2] = -fy*cam1*iz*iz;

        float S[9];
        #pragma unroll
        for (int k = 0; k < 9; ++k) S[k] = covs3d[gi*9+k];

        float RS[9], Cc[9];
        #pragma unroll
        for (int r = 0; r < 3; ++r)
            #pragma unroll
            for (int c = 0; c < 3; ++c)
                RS[r*3+c] = Rl[r*3+0]*S[0+c] + Rl[r*3+1]*S[3+c] + Rl[r*3+2]*S[6+c];
        #pragma unroll
        for (int r = 0; r < 3; ++r)
            #pragma unroll
            for (int c = 0; c < 3; ++c)
                Cc[r*3+c] = RS[r*3+0]*Rl[c*3+0] + RS[r*3+1]*Rl[c*3+1] + RS[r*3+2]*Rl[c*3+2];

        float JC[2][3];
        #pragma unroll
        for (int r = 0; r < 2; ++r)
            #pragma unroll
            for (int c = 0; c < 3; ++c)
                JC[r][c] = J[r][0]*Cc[0+c] + J[r][1]*Cc[3+c] + J[r][2]*Cc[6+c];

        const float c200 = JC[0][0]*J[0][0] + JC[0][1]*J[0][1] + JC[0][2]*J[0][2] + 1e-4f;
        const float c201 = JC[0][0]*J[1][0] + JC[0][1]*J[1][1] + JC[0][2]*J[1][2];
        const float c210 = JC[1][0]*J[0][0] + JC[1][1]*J[0][1] + JC[1][2]*J[0][2];
        const float c211 = JC[1][0]*J[1][0] + JC[1][1]*J[1][1] + JC[1][2]*J[1][2] + 1e-4f;

        const float det  = c200*c211 - c201*c210;
        const float idet = 1.0f / det;
        const float ia   = c211*idet;                    // P00
        const float i01  = -0.5f*(c201 + c210)*idet;     // P01 (symmetrized)
        const float ic   = c200*idet;                    // P11
        const float ibs  = 2.0f*i01;

        const bool  valid = (depth > 1.0f) && (depth < 50.0f);
        const float nrm   = valid ? (INV2PI / sqrtf(det)) : 0.0f;
        const float opn   = opac[gi] * nrm;

        // Exact support test params: Q = ia*(dx+c1*dy)^2 + c2*dy^2 <= L2
        const float c1 = i01 / ia;
        const float c2 = ic - i01*i01/ia;
        const float L2 = 2.0f * logf(opn * INVEPS);      // opn<=0 -> -inf

        rec[0]  = my;  rec[1] = c2;  rec[2] = L2;  rec[3] = c1;
        rec[4]  = mx;  rec[5] = ia;
        rec[6]  = -0.5f*LOG2E*ia;    // A
        rec[7]  = -0.5f*LOG2E*ibs;   // B
        rec[8]  = -0.5f*LOG2E*ic;    // C
        rec[9]  = opn;
        rec[10] = colors[gi*3+0];
        rec[11] = colors[gi*3+1];
        rec[12] = colors[gi*3+2];
    }
    __syncthreads();

    if (act) {
        int rank = 0;
        #pragma unroll
        for (int q = 0; q < 8; ++q) rank += s_cnt[l][q];
        float4* dst = (float4*)(recs + rank*REC);
        dst[0] = make_float4(rec[0],  rec[1],  rec[2],  rec[3]);
        dst[1] = make_float4(rec[4],  rec[5],  rec[6],  rec[7]);
        dst[2] = make_float4(rec[8],  rec[9],  rec[10], rec[11]);
        dst[3] = make_float4(rec[12], 0.0f,    0.0f,    0.0f);
    }
}

// Block: 512 thr = 8 waves; 64x2 row-pair tile. Records LDS-staged once.
__global__ __launch_bounds__(512, 4) void gs_render(
    const float* __restrict__ recs, float* __restrict__ out, int N)
{
    __shared__ float  s_my[512], s_c2[512], s_L2[512], s_c1[512], s_mx[512], s_p0[512];
    __shared__ float  s_ev[512][12];          // 48B rows (16B-aligned)
    __shared__ int    s_hits[SPLIT][64];      // compacted hit indices per wave
    __shared__ float4 s_part[2][SPLIT][64];   // [row][chunk][pixel]
    __shared__ float  s_rgb[2][192];

    const int t = threadIdx.x;

    // Stage: thread t handles record t.
    if (t < N) {
        const float4 a = *(const float4*)(recs + t*REC + 0);   // my,c2,L2,c1
        const float4 b = *(const float4*)(recs + t*REC + 4);   // mx,p00,A,B
        const float4 c = *(const float4*)(recs + t*REC + 8);   // C,opn,r,g
        const float4 d = *(const float4*)(recs + t*REC + 12);  // b,-,-,-
        s_my[t] = a.x; s_c2[t] = a.y; s_L2[t] = a.z; s_c1[t] = a.w;
        s_mx[t] = b.x; s_p0[t] = b.y;
        float4* ev = (float4*)s_ev[t];
        ev[0] = make_float4(b.x, a.x, b.z, b.w);   // mx, my, A, B
        ev[1] = make_float4(c.x, c.y, c.z, c.w);   // C, opn, r, g
        s_ev[t][8] = d.x;                          // blue
    } else {
        s_my[t] = 0.0f; s_c2[t] = 0.0f; s_L2[t] = -1e30f;
        s_c1[t] = 0.0f; s_mx[t] = 0.0f; s_p0[t] = 1.0f;
    }
    __syncthreads();

    const int w    = t >> 6;
    const int lane = t & 63;
    const int xs   = (int)blockIdx.x & 3;
    const int pr   = (int)blockIdx.x >> 2;             // row pair 0..127
    const float y0f = (float)(2*pr);
    const float sx0 = (float)(xs * 64);
    const float scx = sx0 + 31.5f;                     // strip center x
    const float px  = sx0 + (float)lane;

    // Lane-parallel EXACT ellipse test vs rows {y0, y0+1} for chunk w.
    const int base = w * 64;
    bool hit;
    {
        const int j = base + lane;
        const float myj = s_my[j], c2 = s_c2[j], L2 = s_L2[j];
        const float c1  = s_c1[j], mxj = s_mx[j], p0 = s_p0[j];
        float dy  = y0f - myj;
        float rem = fmaf(-c2, dy*dy, L2);
        float xc  = fmaf(-c1, dy, mxj);
        float t1  = fmaxf(fabsf(xc - scx) - 31.5f, 0.0f);
        const bool h0 = (p0*t1*t1 <= rem);
        dy  = dy + 1.0f;
        rem = fmaf(-c2, dy*dy, L2);
        xc  = xc - c1;
        t1  = fmaxf(fabsf(xc - scx) - 31.5f, 0.0f);
        const bool h1 = (p0*t1*t1 <= rem);
        hit = h0 | h1;
    }
    const unsigned long long mask = __ballot(hit);
    const int nhit = __popcll(mask);
    if (hit) {
        const int pos = __popcll(mask & ((1ull << lane) - 1ull));
        s_hits[w][pos] = base + lane;     // ascending = sorted depth order
    }
    // s_hits[w] written & read by the same wave only: no barrier needed.

    float T0 = 1.0f, r0 = 0.0f, g0 = 0.0f, b0 = 0.0f;
    float T1 = 1.0f, r1 = 0.0f, g1 = 0.0f, b1 = 0.0f;

    for (int i = 0; i < nhit; ++i) {
        const int j = s_hits[w][i];                  // broadcast read
        const float* e = s_ev[j];                    // broadcast rows
        const float4 v0 = *(const float4*)(e + 0);   // mx,my,A,B
        const float4 v1 = *(const float4*)(e + 4);   // C,opn,r,g
        const float  bl = e[8];

        const float dx   = px - v0.x;
        const float adx2 = v0.z * dx * dx;           // A*dx^2 (shared)
        const float u    = v0.w * dx;                // B*dx   (shared)
        const float dy0  = y0f - v0.y;
        const float dy1  = dy0 + 1.0f;
        const float e20  = fmaf(dy0, fmaf(v1.x, dy0, u), adx2);
        const float e21  = fmaf(dy1, fmaf(v1.x, dy1, u), adx2);
        const float al0  = v1.y * __builtin_amdgcn_exp2f(e20);
        const float al1  = v1.y * __builtin_amdgcn_exp2f(e21);

        T0 *= (1.0f - al0);                          // cumprod incl. current
        const float w0 = al0 * T0;
        r0 = fmaf(w0, v1.z, r0); g0 = fmaf(w0, v1.w, g0); b0 = fmaf(w0, bl, b0);

        T1 *= (1.0f - al1);
        const float w1 = al1 * T1;
        r1 = fmaf(w1, v1.z, r1); g1 = fmaf(w1, v1.w, g1); b1 = fmaf(w1, bl, b1);
    }

    s_part[0][w][lane] = make_float4(T0, r0, g0, b0);
    s_part[1][w][lane] = make_float4(T1, r1, g1, b1);
    __syncthreads();

    if (t < 128) {
        const int row = t >> 6, p = t & 63;
        float4 f = s_part[row][0][p];
        float Ta = f.x, r_ = f.y, g_ = f.z, b_ = f.w;
        #pragma unroll
        for (int k = 1; k < SPLIT; ++k) {
            const float4 q = s_part[row][k][p];
            r_ = fmaf(Ta, q.y, r_);
            g_ = fmaf(Ta, q.z, g_);
            b_ = fmaf(Ta, q.w, b_);
            Ta *= q.x;
        }
        s_rgb[row][p*3+0] = r_;
        s_rgb[row][p*3+1] = g_;
        s_rgb[row][p*3+2] = b_;
    }
    __syncthreads();

    if (t < 384) {
        const int row = t / 192, i = t - row * 192;
        out[(2*pr + row) * (WIMG*3) + xs*192 + i] = s_rgb[row][i];
    }
}

extern "C" void kernel_launch(void* const* d_in, const int* in_sizes, int n_in,
                              void* d_out, int out_size, void* d_ws, size_t ws_size,
                              hipStream_t stream)
{
    const float* means3D = (const float*)d_in[0];
    const float* covs3d  = (const float*)d_in[1];
    const float* colors  = (const float*)d_in[2];
    const float* opac    = (const float*)d_in[3];
    const float* Km      = (const float*)d_in[4];
    const float* Rm      = (const float*)d_in[5];
    const float* tv      = (const float*)d_in[6];
    const int N = in_sizes[3];               // opacities: (N,)

    float* recs = (float*)d_ws;              // N*REC floats = 32 KB
    float* out  = (float*)d_out;

    gs_preprocess<<<dim3((N + 63) / 64), dim3(512), 0, stream>>>(
        means3D, covs3d, colors, opac, Km, Rm, tv, recs, N);

    gs_render<<<dim3(WIMG * HIMG / 128), dim3(512), 0, stream>>>(recs, out, N);
}